// Round 4
// baseline (99.163 us; speedup 1.0000x reference)
//
#include <hip/hip_runtime.h>

#define K 12
#define NKB 4
#define PIECE_DIM (K * 64)       // 768
#define NROWS (NKB * PIECE_DIM)  // 3072
#define DOUT 128
#define BATCH 16384
#define SEQL 32

typedef float f32x4 __attribute__((ext_vector_type(4)));

// ---------------------------------------------------------------------------
// Kernel 1: build the merged weight table
//   w[nkb,k,r,f,d] = tiles + (pieces + ranks + files)*fmask + noking
// Shape (NKB, K, 8, 8, DOUT) flattened to (3072, 128).
// ---------------------------------------------------------------------------
__global__ __launch_bounds__(DOUT) void build_w_kernel(
    const float* __restrict__ pieces,   // (NKB,K,1,1,DOUT)
    const float* __restrict__ ranks,    // (NKB,K,8,1,DOUT)
    const float* __restrict__ files,    // (NKB,K,1,8,DOUT)
    const float* __restrict__ noking,   // (1,K,8,8,DOUT)
    const float* __restrict__ tiles,    // (NKB,K,8,8,DOUT)
    const float* __restrict__ fmask,    // (NKB,K,8,8,1)
    float* __restrict__ w)              // (NROWS, DOUT)
{
    int row = blockIdx.x;               // 0..3071
    int d   = threadIdx.x;              // 0..127
    int nkb = row / PIECE_DIM;
    int rem = row - nkb * PIECE_DIM;    // 0..767
    int k   = rem >> 6;
    int sq  = rem & 63;
    int r   = sq >> 3;
    int f   = sq & 7;
    int nk_k = nkb * K + k;

    float p  = pieces[nk_k * DOUT + d];
    float rk = ranks[(nk_k * 8 + r) * DOUT + d];
    float fl = files[(nk_k * 8 + f) * DOUT + d];
    float nk = noking[((k * 8 + r) * 8 + f) * DOUT + d];
    float tl = tiles[((nk_k * 8 + r) * 8 + f) * DOUT + d];
    float fm = fmask[(nk_k * 8 + r) * 8 + f];

    w[row * DOUT + d] = tl + (p + rk + fl) * fm + nk;
}

// ---------------------------------------------------------------------------
// KING_BUCKETS: only indices 56,57 -> 3, 60 -> 1, 62,63 -> 2 are nonzero.
// Packed as 2-bit fields in one u64 covering indices 32..63.
// ---------------------------------------------------------------------------
__device__ __forceinline__ int king_bucket(int s) {
    const unsigned long long hi =
        (3ULL << 48) | (3ULL << 50) | (1ULL << 56) | (2ULL << 60) | (2ULL << 62);
    int t = s - 32;
    return (t >= 0) ? (int)((hi >> (2 * t)) & 3ULL) : 0;
}

// ---------------------------------------------------------------------------
// Kernel 2: one wave per batch. Lanes 0-31: mover slice, lanes 32-63: waiter.
// Each lane accumulates one float4 (4 of the 128 channels) over 32 tokens.
// #pragma unroll 1 + one-ahead prefetch keeps <=5 loads in flight so VGPR
// stays ~60 -> 8 waves/SIMD (latency hiding), instead of a fully-unrolled
// 32-deep load cluster that blows the register budget.
// ---------------------------------------------------------------------------
__global__ __launch_bounds__(256) void gather_kernel(
    const int* __restrict__ values,   // (BATCH*SEQL)
    const int* __restrict__ kings,    // (BATCH,2)
    const float* __restrict__ w,      // (NROWS, DOUT)
    float* __restrict__ out)          // a:(BATCH,DOUT) then b:(BATCH,DOUT)
{
    int wave = threadIdx.x >> 6;
    int lane = threadIdx.x & 63;
    int b    = blockIdx.x * 4 + wave;
    int half = lane >> 5;             // 0 = mover, 1 = waiter
    int c    = lane & 31;             // float4 index within the row

    int km   = kings[2 * b];
    int kw   = kings[2 * b + 1];
    int mbkt = king_bucket(km);
    int wbkt = king_bucket(kw ^ 56);  // vertical flip of waiter king square
    int base = (half ? wbkt : mbkt) * PIECE_DIM;

    // Per-lane constants for the value->row transform:
    //   mover  (half=0): rv = v
    //   waiter (half=1): rv = (v ^ 56) + (v < 384 ? +384 : -384)
    int xm = half ? 56 : 0;           // square vertical-flip xor
    int am = half ? -1 : 0;           // mask for the piece +/-6 adjust
    // Per-lane byte offset within w: bucket base row + float4 column.
    int laneoff = (base << 9) + c * 16;

    const int4* vp = (const int4*)(values + b * SEQL);
    const char* wb = (const char*)w;

    f32x4 acc = (f32x4)(0.f);
    int4 cur = vp[0];

    #pragma unroll 1
    for (int j = 0; j < SEQL / 4; ++j) {
        int jn = (j < SEQL / 4 - 1) ? j + 1 : j;
        int4 nxt = vp[jn];            // prefetch next token quad (uniform)
        int vs[4] = {cur.x, cur.y, cur.z, cur.w};
        #pragma unroll
        for (int u = 0; u < 4; ++u) {
            int v   = vs[u];
            int adj = ((v < 384) ? 384 : -384) & am;
            int rv  = (v ^ xm) + adj;
            unsigned off = (unsigned)(laneoff + (rv << 9));
            f32x4 x = *(const f32x4*)(wb + off);
            acc += x;
        }
        cur = nxt;
    }

    acc.x = fminf(fmaxf(acc.x, 0.f), 1.f);
    acc.y = fminf(fmaxf(acc.y, 0.f), 1.f);
    acc.z = fminf(fmaxf(acc.z, 0.f), 1.f);
    acc.w = fminf(fmaxf(acc.w, 0.f), 1.f);

    // Nontemporal store: don't let the 16 MB output stream evict the
    // 1.5 MB w table from the 4 MB/XCD L2.
    f32x4* dst = (f32x4*)(out + (size_t)half * (BATCH * DOUT) + (size_t)b * DOUT) + c;
    __builtin_nontemporal_store(acc, dst);
}

extern "C" void kernel_launch(void* const* d_in, const int* in_sizes, int n_in,
                              void* d_out, int out_size, void* d_ws, size_t ws_size,
                              hipStream_t stream) {
    const int*   values = (const int*)d_in[0];
    // d_in[1] = lengths: uniformly SEQL with BATCH*SEQL == T, so segment b
    // owns tokens [SEQL*b, SEQL*(b+1)) — start offsets computed directly.
    const int*   kings  = (const int*)d_in[2];
    const float* pieces = (const float*)d_in[3];
    const float* ranks  = (const float*)d_in[4];
    const float* files  = (const float*)d_in[5];
    const float* noking = (const float*)d_in[6];
    const float* tiles  = (const float*)d_in[7];
    const float* fmask  = (const float*)d_in[8];

    float* w   = (float*)d_ws;   // needs NROWS*DOUT*4 = 1.5 MB of scratch
    float* out = (float*)d_out;

    build_w_kernel<<<NROWS, DOUT, 0, stream>>>(pieces, ranks, files, noking,
                                               tiles, fmask, w);
    gather_kernel<<<BATCH / 4, 256, 0, stream>>>(values, kings, w, out);
}

// Round 8
// 98.570 us; speedup vs baseline: 1.0060x; 1.0060x over previous
//
#include <hip/hip_runtime.h>

#define K 12
#define NKB 4
#define PIECE_DIM (K * 64)       // 768
#define NROWS (NKB * PIECE_DIM)  // 3072
#define DOUT 128
#define BATCH 16384
#define SEQL 32

typedef float    f32x4 __attribute__((ext_vector_type(4)));
typedef _Float16 f16x4 __attribute__((ext_vector_type(4)));

// ---------------------------------------------------------------------------
// Kernel 1: build the merged weight table in fp16 (halves gather bytes).
//   w[nkb,k,r,f,d] = tiles + (pieces + ranks + files)*fmask + noking
// Shape (NKB, K, 8, 8, DOUT) flattened to (3072, 128), 256 B per row.
// fp16 round-off: |w|*2^-11 ~ 2e-4/elem, 32-term sum -> ~1e-3 absmax,
// far under the 2e-2 harness threshold.
// ---------------------------------------------------------------------------
__global__ __launch_bounds__(DOUT) void build_w_kernel(
    const float* __restrict__ pieces,   // (NKB,K,1,1,DOUT)
    const float* __restrict__ ranks,    // (NKB,K,8,1,DOUT)
    const float* __restrict__ files,    // (NKB,K,1,8,DOUT)
    const float* __restrict__ noking,   // (1,K,8,8,DOUT)
    const float* __restrict__ tiles,    // (NKB,K,8,8,DOUT)
    const float* __restrict__ fmask,    // (NKB,K,8,8,1)
    _Float16* __restrict__ w)           // (NROWS, DOUT) fp16
{
    int row = blockIdx.x;               // 0..3071
    int d   = threadIdx.x;              // 0..127
    int nkb = row / PIECE_DIM;
    int rem = row - nkb * PIECE_DIM;    // 0..767
    int k   = rem >> 6;
    int sq  = rem & 63;
    int r   = sq >> 3;
    int f   = sq & 7;
    int nk_k = nkb * K + k;

    float p  = pieces[nk_k * DOUT + d];
    float rk = ranks[(nk_k * 8 + r) * DOUT + d];
    float fl = files[(nk_k * 8 + f) * DOUT + d];
    float nk = noking[((k * 8 + r) * 8 + f) * DOUT + d];
    float tl = tiles[((nk_k * 8 + r) * 8 + f) * DOUT + d];
    float fm = fmask[(nk_k * 8 + r) * 8 + f];

    w[row * DOUT + d] = (_Float16)(tl + (p + rk + fl) * fm + nk);
}

// ---------------------------------------------------------------------------
// KING_BUCKETS: only indices 56,57 -> 3, 60 -> 1, 62,63 -> 2 are nonzero.
// Packed as 2-bit fields in one u64 covering indices 32..63.
// ---------------------------------------------------------------------------
__device__ __forceinline__ int king_bucket(int s) {
    const unsigned long long hi =
        (3ULL << 48) | (3ULL << 50) | (1ULL << 56) | (2ULL << 60) | (2ULL << 62);
    int t = s - 32;
    return (t >= 0) ? (int)((hi >> (2 * t)) & 3ULL) : 0;
}

// ---------------------------------------------------------------------------
// Kernel 2: one wave per batch. Lanes 0-31: mover slice, lanes 32-63: waiter.
// fp16 rows are 256 B: each lane loads one f16x4 (8 B) per token, converts
// with v_cvt_f32_f16, accumulates in f32. Gather traffic: 256 MB total.
// ---------------------------------------------------------------------------
__global__ __launch_bounds__(256) void gather_kernel(
    const int* __restrict__ values,   // (BATCH*SEQL)
    const int* __restrict__ kings,    // (BATCH,2)
    const _Float16* __restrict__ w,   // (NROWS, DOUT) fp16
    float* __restrict__ out)          // a:(BATCH,DOUT) then b:(BATCH,DOUT)
{
    int wave = threadIdx.x >> 6;
    int lane = threadIdx.x & 63;
    int b    = blockIdx.x * 4 + wave;
    int half = lane >> 5;             // 0 = mover, 1 = waiter
    int c    = lane & 31;             // 4-channel group within the row

    int km   = kings[2 * b];
    int kw   = kings[2 * b + 1];
    int mbkt = king_bucket(km);
    int wbkt = king_bucket(kw ^ 56);  // vertical flip of waiter king square
    int base = (half ? wbkt : mbkt) * PIECE_DIM;

    // value->row transform: mover rv = v; waiter rv = (v^56) +/- 384.
    int xm = half ? 56 : 0;
    int am = half ? -1 : 0;
    // Byte offset: row stride 256 B, lane covers channels [4c, 4c+4).
    int laneoff = (base << 8) + c * 8;

    const int4* vp = (const int4*)(values + b * SEQL);
    const char* wb = (const char*)w;

    f32x4 acc = (f32x4)(0.f);
    int4 cur = vp[0];

    #pragma unroll 1
    for (int j = 0; j < SEQL / 4; ++j) {
        int jn = (j < SEQL / 4 - 1) ? j + 1 : j;
        int4 nxt = vp[jn];            // prefetch next token quad (uniform)
        int vs[4] = {cur.x, cur.y, cur.z, cur.w};
        #pragma unroll
        for (int u = 0; u < 4; ++u) {
            int v   = vs[u];
            int adj = ((v < 384) ? 384 : -384) & am;
            int rv  = (v ^ xm) + adj;
            unsigned off = (unsigned)(laneoff + (rv << 8));
            f16x4 x = *(const f16x4*)(wb + off);
            acc += __builtin_convertvector(x, f32x4);
        }
        cur = nxt;
    }

    acc.x = fminf(fmaxf(acc.x, 0.f), 1.f);
    acc.y = fminf(fmaxf(acc.y, 0.f), 1.f);
    acc.z = fminf(fmaxf(acc.z, 0.f), 1.f);
    acc.w = fminf(fmaxf(acc.w, 0.f), 1.f);

    // Nontemporal store: don't let the 16 MB output stream evict the
    // fp16 w table (768 KB) from the 4 MB/XCD L2.
    f32x4* dst = (f32x4*)(out + (size_t)half * (BATCH * DOUT) + (size_t)b * DOUT) + c;
    __builtin_nontemporal_store(acc, dst);
}

extern "C" void kernel_launch(void* const* d_in, const int* in_sizes, int n_in,
                              void* d_out, int out_size, void* d_ws, size_t ws_size,
                              hipStream_t stream) {
    const int*   values = (const int*)d_in[0];
    // d_in[1] = lengths: uniformly SEQL with BATCH*SEQL == T, so segment b
    // owns tokens [SEQL*b, SEQL*(b+1)) — start offsets computed directly.
    const int*   kings  = (const int*)d_in[2];
    const float* pieces = (const float*)d_in[3];
    const float* ranks  = (const float*)d_in[4];
    const float* files  = (const float*)d_in[5];
    const float* noking = (const float*)d_in[6];
    const float* tiles  = (const float*)d_in[7];
    const float* fmask  = (const float*)d_in[8];

    _Float16* w   = (_Float16*)d_ws;   // NROWS*DOUT*2 = 768 KB of scratch
    float*    out = (float*)d_out;

    build_w_kernel<<<NROWS, DOUT, 0, stream>>>(pieces, ranks, files, noking,
                                               tiles, fmask, w);
    gather_kernel<<<BATCH / 4, 256, 0, stream>>>(values, kings, w, out);
}

// Round 10
// 89.835 us; speedup vs baseline: 1.1038x; 1.0972x over previous
//
#include <hip/hip_runtime.h>

#define K 12
#define NKB 4
#define PIECE_DIM (K * 64)       // 768
#define NROWS (NKB * PIECE_DIM)  // 3072
#define DOUT 128
#define BATCH 16384
#define SEQL 32

typedef float    f32x4 __attribute__((ext_vector_type(4)));
typedef float    f32x8 __attribute__((ext_vector_type(8)));
typedef _Float16 f16x8 __attribute__((ext_vector_type(8)));

// ---------------------------------------------------------------------------
// Kernel 1: build the merged weight table in fp16 (256 B per row).
//   w[nkb,k,r,f,d] = tiles + (pieces + ranks + files)*fmask + noking
// fp16 round-off -> absmax ~4e-3 (measured round 8), threshold 2e-2.
// ---------------------------------------------------------------------------
__global__ __launch_bounds__(DOUT) void build_w_kernel(
    const float* __restrict__ pieces,   // (NKB,K,1,1,DOUT)
    const float* __restrict__ ranks,    // (NKB,K,8,1,DOUT)
    const float* __restrict__ files,    // (NKB,K,1,8,DOUT)
    const float* __restrict__ noking,   // (1,K,8,8,DOUT)
    const float* __restrict__ tiles,    // (NKB,K,8,8,DOUT)
    const float* __restrict__ fmask,    // (NKB,K,8,8,1)
    _Float16* __restrict__ w)           // (NROWS, DOUT) fp16
{
    int row = blockIdx.x;               // 0..3071
    int d   = threadIdx.x;              // 0..127
    int nkb = row / PIECE_DIM;
    int rem = row - nkb * PIECE_DIM;    // 0..767
    int k   = rem >> 6;
    int sq  = rem & 63;
    int r   = sq >> 3;
    int f   = sq & 7;
    int nk_k = nkb * K + k;

    float p  = pieces[nk_k * DOUT + d];
    float rk = ranks[(nk_k * 8 + r) * DOUT + d];
    float fl = files[(nk_k * 8 + f) * DOUT + d];
    float nk = noking[((k * 8 + r) * 8 + f) * DOUT + d];
    float tl = tiles[((nk_k * 8 + r) * 8 + f) * DOUT + d];
    float fm = fmask[(nk_k * 8 + r) * 8 + f];

    w[row * DOUT + d] = (_Float16)(tl + (p + rk + fl) * fm + nk);
}

// ---------------------------------------------------------------------------
// KING_BUCKETS: only indices 56,57 -> 3, 60 -> 1, 62,63 -> 2 are nonzero.
// Packed as 2-bit fields in one u64 covering indices 32..63.
// ---------------------------------------------------------------------------
__device__ __forceinline__ int king_bucket(int s) {
    const unsigned long long hi =
        (3ULL << 48) | (3ULL << 50) | (1ULL << 56) | (2ULL << 60) | (2ULL << 62);
    int t = s - 32;
    return (t >= 0) ? (int)((hi >> (2 * t)) & 3ULL) : 0;
}

// ---------------------------------------------------------------------------
// Kernel 2: one wave per batch, 4 rows gathered PER INSTRUCTION.
// lane = 16*q + c (q in [0,4) = token slot, c in [0,16) = 16B channel group).
// Each f16x8 load instruction covers 4 full 256 B rows (64 lanes x 16 B),
// quartering the VMEM instruction count vs one-row-per-instruction: the
// fp16-null result (round 8) showed the gather is bound by per-lane request
// processing, not bytes. Tokens reach lanes via DS-pipe shfl, not VMEM
// broadcast loads. Final 4-way reduce over q via shfl_xor(16/32).
// ---------------------------------------------------------------------------
__global__ __launch_bounds__(256) void gather_kernel(
    const int* __restrict__ values,   // (BATCH*SEQL)
    const int* __restrict__ kings,    // (BATCH,2)
    const _Float16* __restrict__ w,   // (NROWS, DOUT) fp16
    float* __restrict__ out)          // a:(BATCH,DOUT) then b:(BATCH,DOUT)
{
    int wave = threadIdx.x >> 6;
    int lane = threadIdx.x & 63;
    int b    = blockIdx.x * 4 + wave;
    int q    = lane >> 4;             // token slot within a quad
    int c    = lane & 15;             // 16-byte channel group (8 channels)

    // Cooperative token load: lanes 0-31 hold this batch's 32 values.
    int myv = values[b * SEQL + (lane & 31)];

    int km   = kings[2 * b];
    int kw   = kings[2 * b + 1];
    int mbkt = king_bucket(km);
    int wbkt = king_bucket(kw ^ 56);  // vertical flip of waiter king square

    const char* wbase = (const char*)w;
    // Row stride 256 B; bucket stride PIECE_DIM rows.
    int moff = mbkt * (PIECE_DIM << 8) + c * 16;
    int woff = wbkt * (PIECE_DIM << 8) + c * 16;

    f32x8 accm = (f32x8)(0.f);
    f32x8 accw = (f32x8)(0.f);

    #pragma unroll 1
    for (int j = 0; j < SEQL / 4; ++j) {
        int v  = __shfl(myv, 4 * j + q, 64);          // token 4j+q
        int fv = (v ^ 56) + ((v < 384) ? 384 : -384); // piece+-6, rank flip
        f16x8 xm = *(const f16x8*)(wbase + moff + (v  << 8));
        f16x8 xw = *(const f16x8*)(wbase + woff + (fv << 8));
        accm += __builtin_convertvector(xm, f32x8);
        accw += __builtin_convertvector(xw, f32x8);
    }

    // Sum the 4 token slots (lanes differing in bits 4,5), then clip.
    #pragma unroll
    for (int e = 0; e < 8; ++e) {
        accm[e] += __shfl_xor(accm[e], 16, 64);
        accm[e] += __shfl_xor(accm[e], 32, 64);
        accw[e] += __shfl_xor(accw[e], 16, 64);
        accw[e] += __shfl_xor(accw[e], 32, 64);
        accm[e] = fminf(fmaxf(accm[e], 0.f), 1.f);
        accw[e] = fminf(fmaxf(accw[e], 0.f), 1.f);
    }

    // q==0 lanes store mover row, q==1 lanes store waiter row (NT: keep the
    // 768 KB w table resident in L2 against the 16 MB output stream).
    if (q == 0) {
        f32x4* dst = (f32x4*)(out + (size_t)b * DOUT + c * 8);
        f32x4 lo = {accm[0], accm[1], accm[2], accm[3]};
        f32x4 hi = {accm[4], accm[5], accm[6], accm[7]};
        __builtin_nontemporal_store(lo, dst);
        __builtin_nontemporal_store(hi, dst + 1);
    } else if (q == 1) {
        f32x4* dst = (f32x4*)(out + (size_t)(BATCH + b) * DOUT + c * 8);
        f32x4 lo = {accw[0], accw[1], accw[2], accw[3]};
        f32x4 hi = {accw[4], accw[5], accw[6], accw[7]};
        __builtin_nontemporal_store(lo, dst);
        __builtin_nontemporal_store(hi, dst + 1);
    }
}

extern "C" void kernel_launch(void* const* d_in, const int* in_sizes, int n_in,
                              void* d_out, int out_size, void* d_ws, size_t ws_size,
                              hipStream_t stream) {
    const int*   values = (const int*)d_in[0];
    // d_in[1] = lengths: uniformly SEQL with BATCH*SEQL == T, so segment b
    // owns tokens [SEQL*b, SEQL*(b+1)) — start offsets computed directly.
    const int*   kings  = (const int*)d_in[2];
    const float* pieces = (const float*)d_in[3];
    const float* ranks  = (const float*)d_in[4];
    const float* files  = (const float*)d_in[5];
    const float* noking = (const float*)d_in[6];
    const float* tiles  = (const float*)d_in[7];
    const float* fmask  = (const float*)d_in[8];

    _Float16* w   = (_Float16*)d_ws;   // NROWS*DOUT*2 = 768 KB of scratch
    float*    out = (float*)d_out;

    build_w_kernel<<<NROWS, DOUT, 0, stream>>>(pieces, ranks, files, noking,
                                               tiles, fmask, w);
    gather_kernel<<<BATCH / 4, 256, 0, stream>>>(values, kings, w, out);
}

// Round 11
// 88.818 us; speedup vs baseline: 1.1165x; 1.0114x over previous
//
#include <hip/hip_runtime.h>

#define K 12
#define NKB 4
#define PIECE_DIM (K * 64)       // 768
#define NROWS (NKB * PIECE_DIM)  // 3072
#define DOUT 128
#define BATCH 16384
#define SEQL 32

typedef float    f32x4 __attribute__((ext_vector_type(4)));
typedef float    f32x8 __attribute__((ext_vector_type(8)));
typedef _Float16 f16x8 __attribute__((ext_vector_type(8)));

// ---------------------------------------------------------------------------
// Kernel 1: build the merged weight table in fp16 (256 B per row).
//   w[nkb,k,r,f,d] = tiles + (pieces + ranks + files)*fmask + noking
// fp16 round-off -> absmax ~4e-3 (measured round 8), threshold 2e-2.
// ---------------------------------------------------------------------------
__global__ __launch_bounds__(DOUT) void build_w_kernel(
    const float* __restrict__ pieces,   // (NKB,K,1,1,DOUT)
    const float* __restrict__ ranks,    // (NKB,K,8,1,DOUT)
    const float* __restrict__ files,    // (NKB,K,1,8,DOUT)
    const float* __restrict__ noking,   // (1,K,8,8,DOUT)
    const float* __restrict__ tiles,    // (NKB,K,8,8,DOUT)
    const float* __restrict__ fmask,    // (NKB,K,8,8,1)
    _Float16* __restrict__ w)           // (NROWS, DOUT) fp16
{
    int row = blockIdx.x;               // 0..3071
    int d   = threadIdx.x;              // 0..127
    int nkb = row / PIECE_DIM;
    int rem = row - nkb * PIECE_DIM;    // 0..767
    int k   = rem >> 6;
    int sq  = rem & 63;
    int r   = sq >> 3;
    int f   = sq & 7;
    int nk_k = nkb * K + k;

    float p  = pieces[nk_k * DOUT + d];
    float rk = ranks[(nk_k * 8 + r) * DOUT + d];
    float fl = files[(nk_k * 8 + f) * DOUT + d];
    float nk = noking[((k * 8 + r) * 8 + f) * DOUT + d];
    float tl = tiles[((nk_k * 8 + r) * 8 + f) * DOUT + d];
    float fm = fmask[(nk_k * 8 + r) * 8 + f];

    w[row * DOUT + d] = (_Float16)(tl + (p + rk + fl) * fm + nk);
}

// ---------------------------------------------------------------------------
// KING_BUCKETS: only indices 56,57 -> 3, 60 -> 1, 62,63 -> 2 are nonzero.
// Packed as 2-bit fields in one u64 covering indices 32..63.
// ---------------------------------------------------------------------------
__device__ __forceinline__ int king_bucket(int s) {
    const unsigned long long hi =
        (3ULL << 48) | (3ULL << 50) | (1ULL << 56) | (2ULL << 60) | (2ULL << 62);
    int t = s - 32;
    return (t >= 0) ? (int)((hi >> (2 * t)) & 3ULL) : 0;
}

// ---------------------------------------------------------------------------
// Kernel 2: one wave per batch, 4 rows per gather instruction
// (lane = 16q + c), software-pipelined in 16-token groups:
//   phase A: 4 shfls + all address math  -> 8 addresses
//   phase B: issue all 8 f16x8 gathers   -> 8 loads in flight (MLP x4)
//   phase C: convert + accumulate
// Tests latency-bound vs line-throughput-bound: round-10's unroll-1 loop
// exposed L2 latency once per 4 tokens; this exposes it once per 16.
// ---------------------------------------------------------------------------
__global__ __launch_bounds__(256) void gather_kernel(
    const int* __restrict__ values,   // (BATCH*SEQL)
    const int* __restrict__ kings,    // (BATCH,2)
    const _Float16* __restrict__ w,   // (NROWS, DOUT) fp16
    float* __restrict__ out)          // a:(BATCH,DOUT) then b:(BATCH,DOUT)
{
    int wave = threadIdx.x >> 6;
    int lane = threadIdx.x & 63;
    int b    = blockIdx.x * 4 + wave;
    int q    = lane >> 4;             // token slot within a quad
    int c    = lane & 15;             // 16-byte channel group (8 channels)

    // Cooperative token load: lanes 0-31 hold this batch's 32 values.
    int myv = values[b * SEQL + (lane & 31)];

    int km   = kings[2 * b];
    int kw   = kings[2 * b + 1];
    int mbkt = king_bucket(km);
    int wbkt = king_bucket(kw ^ 56);  // vertical flip of waiter king square

    const char* wbase = (const char*)w;
    // Row stride 256 B; bucket stride PIECE_DIM rows.
    int moff = mbkt * (PIECE_DIM << 8) + c * 16;
    int woff = wbkt * (PIECE_DIM << 8) + c * 16;

    f32x8 accm = (f32x8)(0.f);
    f32x8 accw = (f32x8)(0.f);

    #pragma unroll 1
    for (int g = 0; g < 2; ++g) {     // 16 tokens per group
        // --- phase A: all shuffles + address math for this group ---
        int off_m[4], off_w[4];
        #pragma unroll
        for (int t = 0; t < 4; ++t) {
            int v  = __shfl(myv, 16 * g + 4 * t + q, 64);
            int fv = (v ^ 56) + ((v < 384) ? 384 : -384);
            off_m[t] = moff + (v  << 8);
            off_w[t] = woff + (fv << 8);
        }
        // --- phase B: issue all 8 gathers (8 loads in flight) ---
        f16x8 xm[4], xw[4];
        #pragma unroll
        for (int t = 0; t < 4; ++t) {
            xm[t] = *(const f16x8*)(wbase + off_m[t]);
            xw[t] = *(const f16x8*)(wbase + off_w[t]);
        }
        // --- phase C: convert + accumulate ---
        #pragma unroll
        for (int t = 0; t < 4; ++t) {
            accm += __builtin_convertvector(xm[t], f32x8);
            accw += __builtin_convertvector(xw[t], f32x8);
        }
    }

    // Sum the 4 token slots (lanes differing in bits 4,5), then clip.
    #pragma unroll
    for (int e = 0; e < 8; ++e) {
        accm[e] += __shfl_xor(accm[e], 16, 64);
        accm[e] += __shfl_xor(accm[e], 32, 64);
        accw[e] += __shfl_xor(accw[e], 16, 64);
        accw[e] += __shfl_xor(accw[e], 32, 64);
        accm[e] = fminf(fmaxf(accm[e], 0.f), 1.f);
        accw[e] = fminf(fmaxf(accw[e], 0.f), 1.f);
    }

    // q==0 lanes store mover row, q==1 lanes store waiter row (NT: keep the
    // 768 KB w table resident in L2 against the 16 MB output stream).
    if (q == 0) {
        f32x4* dst = (f32x4*)(out + (size_t)b * DOUT + c * 8);
        f32x4 lo = {accm[0], accm[1], accm[2], accm[3]};
        f32x4 hi = {accm[4], accm[5], accm[6], accm[7]};
        __builtin_nontemporal_store(lo, dst);
        __builtin_nontemporal_store(hi, dst + 1);
    } else if (q == 1) {
        f32x4* dst = (f32x4*)(out + (size_t)(BATCH + b) * DOUT + c * 8);
        f32x4 lo = {accw[0], accw[1], accw[2], accw[3]};
        f32x4 hi = {accw[4], accw[5], accw[6], accw[7]};
        __builtin_nontemporal_store(lo, dst);
        __builtin_nontemporal_store(hi, dst + 1);
    }
}

extern "C" void kernel_launch(void* const* d_in, const int* in_sizes, int n_in,
                              void* d_out, int out_size, void* d_ws, size_t ws_size,
                              hipStream_t stream) {
    const int*   values = (const int*)d_in[0];
    // d_in[1] = lengths: uniformly SEQL with BATCH*SEQL == T, so segment b
    // owns tokens [SEQL*b, SEQL*(b+1)) — start offsets computed directly.
    const int*   kings  = (const int*)d_in[2];
    const float* pieces = (const float*)d_in[3];
    const float* ranks  = (const float*)d_in[4];
    const float* files  = (const float*)d_in[5];
    const float* noking = (const float*)d_in[6];
    const float* tiles  = (const float*)d_in[7];
    const float* fmask  = (const float*)d_in[8];

    _Float16* w   = (_Float16*)d_ws;   // NROWS*DOUT*2 = 768 KB of scratch
    float*    out = (float*)d_out;

    build_w_kernel<<<NROWS, DOUT, 0, stream>>>(pieces, ranks, files, noking,
                                               tiles, fmask, w);
    gather_kernel<<<BATCH / 4, 256, 0, stream>>>(values, kings, w, out);
}